// Round 13
// baseline (89.494 us; speedup 1.0000x reference)
//
#include <hip/hip_runtime.h>

// YOLO decode, fused: feat13 [256,255,13,13] + feat26 [256,255,26,26]
//   -> out [256, 2535, 85] fp32   (2535 = 3*169 + 3*676)
//
// R13 = R12 (best: 69.8 us) + STREAMING stores (sc0 sc1 nt).
//  - R12 proven: W=104 tiles, 512-thr blocks, 35.4 KB LDS, full decode in
//    staging, wave-autonomous head26, pure LDS->global copy store, bijective
//    chunked XCD swizzle (FETCH 140.8 -> 107.9 MB, seam L2 reuse).
//  - NEW: stores use inline-asm `global_store_* off sc0 sc1 nt` = system-
//    scope nontemporal -> no-allocate in L2 AND LLC. Input (220.6 MB) fits
//    L3 (256 MB) alone; R12's FETCH=108 MB == input lines evicted by our
//    own 224 MB output allocating in L3 (plain `nt` doesn't prevent that —
//    R5 A/B). If output bypasses L3, input stays resident across replays ->
//    FETCH -> ~0 steady-state, HBM carries only the write stream.

#define ROWS 2535
#define H26_BLOCKS (256 * 3 * 7)    // ceil(676/104) = 7 tiles (last W=52)
#define H13_BLOCKS (256 * 3 * 2)    // ceil(169/104) = 2 tiles (last W=65)
#define NWG (H26_BLOCKS + H13_BLOCKS)   // 6912, % 8 == 0

typedef float vf4 __attribute__((ext_vector_type(4)));

__device__ __forceinline__ float fsig(float v) {
    return __builtin_amdgcn_rcpf(1.0f + __expf(-v));
}

// ---- streaming stores: system-scope nontemporal (no L2/LLC allocate) ----
__device__ __forceinline__ void st_stream_v4(float* p, vf4 v) {
    asm volatile("global_store_dwordx4 %0, %1, off sc0 sc1 nt"
                 :: "v"(p), "v"(v) : "memory");
}
__device__ __forceinline__ void st_stream_f(float* p, float v) {
    asm volatile("global_store_dword %0, %1, off sc0 sc1 nt"
                 :: "v"(p), "v"(v) : "memory");
}

// ---- pure-copy store over [j_lo, j_hi) by one wave ----
__device__ __forceinline__ void copy_phase_wave(
    const float* __restrict__ lds, float* __restrict__ dst, int mis,
    int j_lo, int j_hi)
{
    const int lane = threadIdx.x & 63;
    const int kk  = (4 - ((mis + j_lo) & 3)) & 3;   // scalars to 16B boundary
    const int qlo = j_lo + kk;
    const int nq  = (j_hi - qlo) >> 2;

    if (lane < kk && j_lo + lane < j_hi)
        st_stream_f(dst + j_lo + lane, lds[mis + j_lo + lane]);
    for (int q = lane; q < nq; q += 64) {
        int j0 = qlo + q * 4;
        const vf4 v = *(const vf4*)(lds + mis + j0);    // 16B-aligned b128
        st_stream_v4(dst + j0, v);
    }
    for (int j = qlo + nq * 4 + lane; j < j_hi; j += 64)
        st_stream_f(dst + j, lds[mis + j]);
}

// ---- pure-copy store, block-wide (head13, after __syncthreads) ----
__device__ __forceinline__ void copy_phase_block(
    const float* __restrict__ lds, float* __restrict__ dst, int mis, int n)
{
    const int t  = threadIdx.x;
    const int kk = (4 - mis) & 3;
    const int nq = (n - kk) >> 2;
    if (t < kk)
        st_stream_f(dst + t, lds[mis + t]);
    for (int q = t; q < nq; q += 512) {
        int j0 = q * 4 + kk;
        const vf4 v = *(const vf4*)(lds + mis + j0);
        st_stream_v4(dst + j0, v);
    }
    for (int j = kk + nq * 4 + t; j < n; j += 512)
        st_stream_f(dst + j, lds[mis + j]);
}

__device__ __forceinline__ void head26_body(
    const float* __restrict__ f, float* __restrict__ out, float* __restrict__ lds,
    int bid)
{
    constexpr int GG = 676, TPP = 7;
    const int tile = bid % TPP;       // constexpr divisors -> magic mul
    const int ba   = bid / TPP;
    const int a    = ba % 3;
    const int b    = ba / 3;
    const int s0   = tile * 104;      // s0 % 26 == 0
    const int W    = (GG - s0 < 104) ? (GG - s0) : 104;   // 104 or 52
    const int C4   = W >> 2;          // 26 or 13 vf4-columns

    const float aw = (a == 0) ? 10.f : (a == 1) ? 23.f : 37.f;
    const float ah = (a == 0) ? 14.f : (a == 1) ? 27.f : 58.f;

    const float* __restrict__ src = f + (size_t)(b * 255 + a * 85) * GG + s0;
    float* __restrict__ dst = out + ((size_t)b * ROWS + 507 + (size_t)a * GG + s0) * 85;
    const int mis  = (int)(((size_t)dst >> 2) & 3);
    const int wave = threadIdx.x >> 6;
    const int lane = threadIdx.x & 63;

    // column split across 8 waves:
    //   C4=26: waves 0,1 -> 4 cols; waves 2..7 -> 3 cols
    //   C4=13: waves 0..4 -> 2 cols; waves 5..7 -> 1 col
    int lo, nw4;
    if (C4 == 26) { nw4 = (wave < 2) ? 4 : 3;
                    lo  = (wave < 2) ? wave * 4 : 8 + (wave - 2) * 3; }
    else          { nw4 = (wave < 5) ? 2 : 1;
                    lo  = (wave < 5) ? wave * 2 : 10 + (wave - 5); }
    const int nitems = 85 * nw4;      // <= 340 -> <= 6 rounds of 64 lanes

    // c-major item decomposition (wave-uniform divisor selection)
    #define DECOMP(i, c, w4r)                                   \
        do { if (nw4 == 4)      { c = (i) >> 2; w4r = (i) & 3; }\
             else if (nw4 == 3) { c = (i) / 3;  w4r = (i) - c * 3; }\
             else if (nw4 == 2) { c = (i) >> 1; w4r = (i) & 1; }\
             else               { c = (i);      w4r = 0; } } while (0)

    // ---- batched loads ----
    vf4 V[6];
    #pragma unroll
    for (int r = 0; r < 6; ++r) {
        int i = lane + r * 64;
        if (i < nitems) {
            int c, w4r; DECOMP(i, c, w4r);
            V[r] = *(const vf4*)(src + (size_t)c * GG + (lo + w4r) * 4);
        }
    }

    // ---- decode + LDS write (FINAL values; stride 85 = odd bank step) ----
    #pragma unroll
    for (int r = 0; r < 6; ++r) {
        int i = lane + r * 64;
        if (i < nitems) {
            int c, w4r; DECOMP(i, c, w4r);
            const int wb   = (lo + w4r) * 4;            // spatial w of V[r].x
            const int base = mis + wb * 85 + c;
            const vf4 v = V[r];
            if (c >= 4) {
                lds[base]       = fsig(v.x);
                lds[base + 85]  = fsig(v.y);
                lds[base + 170] = fsig(v.z);
                lds[base + 255] = fsig(v.w);
            } else if (c == 0) {
                #pragma unroll
                for (int e = 0; e < 4; ++e) {
                    int w = wb + e;
                    int k26 = w / 26;                   // const div, 0..3
                    int gx  = w - k26 * 26;
                    lds[base + e * 85] = (fsig(v[e]) + (float)gx) * 16.0f;
                }
            } else if (c == 1) {
                #pragma unroll
                for (int e = 0; e < 4; ++e) {
                    int w = wb + e;
                    int k26 = w / 26;
                    int gy  = tile * 4 + k26;           // s0/26 = tile*4
                    lds[base + e * 85] = (fsig(v[e]) + (float)gy) * 16.0f;
                }
            } else {
                #pragma unroll
                for (int e = 0; e < 4; ++e)
                    lds[base + e * 85] = __expf(v[e]) * ((c == 2) ? aw : ah);
            }
        }
    }
    #undef DECOMP

    // wave-local LDS fence (no block barrier)
    asm volatile("s_waitcnt lgkmcnt(0)" ::: "memory");
    __builtin_amdgcn_sched_barrier(0);

    copy_phase_wave(lds, dst, mis, lo * 340, (lo + nw4) * 340);
}

__device__ __forceinline__ void head13_body(
    const float* __restrict__ f, float* __restrict__ out, float* __restrict__ lds,
    int bid)
{
    constexpr int GG = 169, TPP = 2;
    const int tile = bid % TPP;
    const int ba   = bid / TPP;
    const int a    = ba % 3;
    const int b    = ba / 3;
    const int s0   = tile * 104;      // s0 % 13 == 0
    const int W    = (GG - s0 < 104) ? (GG - s0) : 104;   // 104, 65

    const float aw = (a == 0) ? 81.f : (a == 1) ? 135.f : 344.f;
    const float ah = (a == 0) ? 82.f : (a == 1) ? 169.f : 319.f;

    const float* __restrict__ src = f + (size_t)(b * 255 + a * 85) * GG;
    float* __restrict__ dst = out + ((size_t)b * ROWS + (size_t)a * GG + s0) * 85;
    const int mis = (int)(((size_t)dst >> 2) & 3);
    const int t = threadIdx.x;

    // ---- load phase: 42 pairs x 104 w-slots = 4368 items, 9 rounds ----
    float A[9], B[9], Lv;
    #pragma unroll
    for (int k = 0; k < 9; ++k) {
        int i = t + k * 512;
        int p = i / 104;              // const div
        int w = i - p * 104;
        if ((k < 8 || i < 4368) && (w < W)) {
            const float* s = src + (size_t)(2 * p) * GG + s0 + w;
            A[k] = s[0];
            B[k] = s[GG];
        }
    }
    const bool okL = t < W;                   // leftover channel c=84
    if (okL) Lv = src[(size_t)84 * GG + s0 + t];

    // ---- decode + write phase (FINAL values) ----
    #pragma unroll
    for (int k = 0; k < 9; ++k) {
        int i = t + k * 512;
        int p = i / 104;
        int w = i - p * 104;
        if ((k < 8 || i < 4368) && (w < W)) {
            int base = mis + w * 85 + 2 * p;
            if (p >= 2) {
                lds[base]     = fsig(A[k]);
                lds[base + 1] = fsig(B[k]);
            } else if (p == 0) {
                int t13 = w / 13;             // const div, 0..7
                int gx  = w - t13 * 13;
                int gy  = tile * 8 + t13;     // s0/13 = tile*8
                lds[base]     = (fsig(A[k]) + (float)gx) * 32.0f;
                lds[base + 1] = (fsig(B[k]) + (float)gy) * 32.0f;
            } else {
                lds[base]     = __expf(A[k]) * aw;
                lds[base + 1] = __expf(B[k]) * ah;
            }
        }
    }
    if (okL) lds[mis + t * 85 + 84] = fsig(Lv);
    __syncthreads();

    copy_phase_block(lds, dst, mis, W * 85);
}

__global__ __launch_bounds__(512, 8) void yolo_fused(
    const float* __restrict__ f13, const float* __restrict__ f26,
    float* __restrict__ out)
{
    __shared__ __align__(16) float lds[104 * 85 + 4];  // 35.4 KB -> 4 blk/CU
    // Bijective chunked XCD swizzle (NWG % 8 == 0): consecutive original
    // bids (adjacent tiles of one plane) -> same XCD, dispatch slots 8 apart.
    const int w   = blockIdx.x;
    const int bid = (w & 7) * (NWG / 8) + (w >> 3);
    if (bid < H26_BLOCKS) head26_body(f26, out, lds, bid);
    else                  head13_body(f13, out, lds, bid - H26_BLOCKS);
}

extern "C" void kernel_launch(void* const* d_in, const int* in_sizes, int n_in,
                              void* d_out, int out_size, void* d_ws, size_t ws_size,
                              hipStream_t stream) {
    const float* f13 = (const float*)d_in[0];
    const float* f26 = (const float*)d_in[1];
    float* out = (float*)d_out;
    yolo_fused<<<NWG, 512, 0, stream>>>(f13, f26, out);
}

// Round 14
// 89.443 us; speedup vs baseline: 1.0006x; 1.0006x over previous
//
#include <hip/hip_runtime.h>

// YOLO decode, fused: feat13 [256,255,13,13] + feat26 [256,255,26,26]
//   -> out [256, 2535, 85] fp32   (2535 = 3*169 + 3*676)
//
// R14 = R12 (best: 69.8 us) + CORRECTED streaming stores (`sc1 nt`).
//  - R13 used `sc0 sc1 nt`: {sc1,sc0}=11 is the RESERVED scope encoding on
//    CDNA — write path collapsed (89.5 us). Correct system-scope streaming
//    is {sc1,sc0}=10, i.e. `sc1 nt` (no sc0).
//  - Theory under test (unchanged): our 224 MB output allocating in the
//    256 MB LLC evicts the 220.6 MB input -> 108 MB/replay input re-fetch
//    (R12 FETCH_SIZE). If `sc1 nt` stores skip LLC allocation with write
//    combining intact, input stays LLC-resident across replays: FETCH -> ~0,
//    HBM carries only the write stream.
//  - Everything else byte-identical to R12: W=104 tiles, 512-thr blocks,
//    35.4 KB LDS (4 blk/CU), full decode in staging, wave-autonomous head26
//    (wave-local lgkmcnt fence, no barrier), pure LDS->global copy store,
//    bijective chunked XCD swizzle.

#define ROWS 2535
#define H26_BLOCKS (256 * 3 * 7)    // ceil(676/104) = 7 tiles (last W=52)
#define H13_BLOCKS (256 * 3 * 2)    // ceil(169/104) = 2 tiles (last W=65)
#define NWG (H26_BLOCKS + H13_BLOCKS)   // 6912, % 8 == 0

typedef float vf4 __attribute__((ext_vector_type(4)));

__device__ __forceinline__ float fsig(float v) {
    return __builtin_amdgcn_rcpf(1.0f + __expf(-v));
}

// ---- streaming stores: system-scope nontemporal, {sc1,sc0}=10 ----
__device__ __forceinline__ void st_stream_v4(float* p, vf4 v) {
    asm volatile("global_store_dwordx4 %0, %1, off sc1 nt"
                 :: "v"(p), "v"(v) : "memory");
}
__device__ __forceinline__ void st_stream_f(float* p, float v) {
    asm volatile("global_store_dword %0, %1, off sc1 nt"
                 :: "v"(p), "v"(v) : "memory");
}

// ---- pure-copy store over [j_lo, j_hi) by one wave ----
__device__ __forceinline__ void copy_phase_wave(
    const float* __restrict__ lds, float* __restrict__ dst, int mis,
    int j_lo, int j_hi)
{
    const int lane = threadIdx.x & 63;
    const int kk  = (4 - ((mis + j_lo) & 3)) & 3;   // scalars to 16B boundary
    const int qlo = j_lo + kk;
    const int nq  = (j_hi - qlo) >> 2;

    if (lane < kk && j_lo + lane < j_hi)
        st_stream_f(dst + j_lo + lane, lds[mis + j_lo + lane]);
    for (int q = lane; q < nq; q += 64) {
        int j0 = qlo + q * 4;
        const vf4 v = *(const vf4*)(lds + mis + j0);    // 16B-aligned b128
        st_stream_v4(dst + j0, v);
    }
    for (int j = qlo + nq * 4 + lane; j < j_hi; j += 64)
        st_stream_f(dst + j, lds[mis + j]);
}

// ---- pure-copy store, block-wide (head13, after __syncthreads) ----
__device__ __forceinline__ void copy_phase_block(
    const float* __restrict__ lds, float* __restrict__ dst, int mis, int n)
{
    const int t  = threadIdx.x;
    const int kk = (4 - mis) & 3;
    const int nq = (n - kk) >> 2;
    if (t < kk)
        st_stream_f(dst + t, lds[mis + t]);
    for (int q = t; q < nq; q += 512) {
        int j0 = q * 4 + kk;
        const vf4 v = *(const vf4*)(lds + mis + j0);
        st_stream_v4(dst + j0, v);
    }
    for (int j = kk + nq * 4 + t; j < n; j += 512)
        st_stream_f(dst + j, lds[mis + j]);
}

__device__ __forceinline__ void head26_body(
    const float* __restrict__ f, float* __restrict__ out, float* __restrict__ lds,
    int bid)
{
    constexpr int GG = 676, TPP = 7;
    const int tile = bid % TPP;       // constexpr divisors -> magic mul
    const int ba   = bid / TPP;
    const int a    = ba % 3;
    const int b    = ba / 3;
    const int s0   = tile * 104;      // s0 % 26 == 0
    const int W    = (GG - s0 < 104) ? (GG - s0) : 104;   // 104 or 52
    const int C4   = W >> 2;          // 26 or 13 vf4-columns

    const float aw = (a == 0) ? 10.f : (a == 1) ? 23.f : 37.f;
    const float ah = (a == 0) ? 14.f : (a == 1) ? 27.f : 58.f;

    const float* __restrict__ src = f + (size_t)(b * 255 + a * 85) * GG + s0;
    float* __restrict__ dst = out + ((size_t)b * ROWS + 507 + (size_t)a * GG + s0) * 85;
    const int mis  = (int)(((size_t)dst >> 2) & 3);
    const int wave = threadIdx.x >> 6;
    const int lane = threadIdx.x & 63;

    // column split across 8 waves:
    //   C4=26: waves 0,1 -> 4 cols; waves 2..7 -> 3 cols
    //   C4=13: waves 0..4 -> 2 cols; waves 5..7 -> 1 col
    int lo, nw4;
    if (C4 == 26) { nw4 = (wave < 2) ? 4 : 3;
                    lo  = (wave < 2) ? wave * 4 : 8 + (wave - 2) * 3; }
    else          { nw4 = (wave < 5) ? 2 : 1;
                    lo  = (wave < 5) ? wave * 2 : 10 + (wave - 5); }
    const int nitems = 85 * nw4;      // <= 340 -> <= 6 rounds of 64 lanes

    // c-major item decomposition (wave-uniform divisor selection)
    #define DECOMP(i, c, w4r)                                   \
        do { if (nw4 == 4)      { c = (i) >> 2; w4r = (i) & 3; }\
             else if (nw4 == 3) { c = (i) / 3;  w4r = (i) - c * 3; }\
             else if (nw4 == 2) { c = (i) >> 1; w4r = (i) & 1; }\
             else               { c = (i);      w4r = 0; } } while (0)

    // ---- batched loads ----
    vf4 V[6];
    #pragma unroll
    for (int r = 0; r < 6; ++r) {
        int i = lane + r * 64;
        if (i < nitems) {
            int c, w4r; DECOMP(i, c, w4r);
            V[r] = *(const vf4*)(src + (size_t)c * GG + (lo + w4r) * 4);
        }
    }

    // ---- decode + LDS write (FINAL values; stride 85 = odd bank step) ----
    #pragma unroll
    for (int r = 0; r < 6; ++r) {
        int i = lane + r * 64;
        if (i < nitems) {
            int c, w4r; DECOMP(i, c, w4r);
            const int wb   = (lo + w4r) * 4;            // spatial w of V[r].x
            const int base = mis + wb * 85 + c;
            const vf4 v = V[r];
            if (c >= 4) {
                lds[base]       = fsig(v.x);
                lds[base + 85]  = fsig(v.y);
                lds[base + 170] = fsig(v.z);
                lds[base + 255] = fsig(v.w);
            } else if (c == 0) {
                #pragma unroll
                for (int e = 0; e < 4; ++e) {
                    int w = wb + e;
                    int k26 = w / 26;                   // const div, 0..3
                    int gx  = w - k26 * 26;
                    lds[base + e * 85] = (fsig(v[e]) + (float)gx) * 16.0f;
                }
            } else if (c == 1) {
                #pragma unroll
                for (int e = 0; e < 4; ++e) {
                    int w = wb + e;
                    int k26 = w / 26;
                    int gy  = tile * 4 + k26;           // s0/26 = tile*4
                    lds[base + e * 85] = (fsig(v[e]) + (float)gy) * 16.0f;
                }
            } else {
                #pragma unroll
                for (int e = 0; e < 4; ++e)
                    lds[base + e * 85] = __expf(v[e]) * ((c == 2) ? aw : ah);
            }
        }
    }
    #undef DECOMP

    // wave-local LDS fence (no block barrier)
    asm volatile("s_waitcnt lgkmcnt(0)" ::: "memory");
    __builtin_amdgcn_sched_barrier(0);

    copy_phase_wave(lds, dst, mis, lo * 340, (lo + nw4) * 340);
}

__device__ __forceinline__ void head13_body(
    const float* __restrict__ f, float* __restrict__ out, float* __restrict__ lds,
    int bid)
{
    constexpr int GG = 169, TPP = 2;
    const int tile = bid % TPP;
    const int ba   = bid / TPP;
    const int a    = ba % 3;
    const int b    = ba / 3;
    const int s0   = tile * 104;      // s0 % 13 == 0
    const int W    = (GG - s0 < 104) ? (GG - s0) : 104;   // 104, 65

    const float aw = (a == 0) ? 81.f : (a == 1) ? 135.f : 344.f;
    const float ah = (a == 0) ? 82.f : (a == 1) ? 169.f : 319.f;

    const float* __restrict__ src = f + (size_t)(b * 255 + a * 85) * GG;
    float* __restrict__ dst = out + ((size_t)b * ROWS + (size_t)a * GG + s0) * 85;
    const int mis = (int)(((size_t)dst >> 2) & 3);
    const int t = threadIdx.x;

    // ---- load phase: 42 pairs x 104 w-slots = 4368 items, 9 rounds ----
    float A[9], B[9], Lv;
    #pragma unroll
    for (int k = 0; k < 9; ++k) {
        int i = t + k * 512;
        int p = i / 104;              // const div
        int w = i - p * 104;
        if ((k < 8 || i < 4368) && (w < W)) {
            const float* s = src + (size_t)(2 * p) * GG + s0 + w;
            A[k] = s[0];
            B[k] = s[GG];
        }
    }
    const bool okL = t < W;                   // leftover channel c=84
    if (okL) Lv = src[(size_t)84 * GG + s0 + t];

    // ---- decode + write phase (FINAL values) ----
    #pragma unroll
    for (int k = 0; k < 9; ++k) {
        int i = t + k * 512;
        int p = i / 104;
        int w = i - p * 104;
        if ((k < 8 || i < 4368) && (w < W)) {
            int base = mis + w * 85 + 2 * p;
            if (p >= 2) {
                lds[base]     = fsig(A[k]);
                lds[base + 1] = fsig(B[k]);
            } else if (p == 0) {
                int t13 = w / 13;             // const div, 0..7
                int gx  = w - t13 * 13;
                int gy  = tile * 8 + t13;     // s0/13 = tile*8
                lds[base]     = (fsig(A[k]) + (float)gx) * 32.0f;
                lds[base + 1] = (fsig(B[k]) + (float)gy) * 32.0f;
            } else {
                lds[base]     = __expf(A[k]) * aw;
                lds[base + 1] = __expf(B[k]) * ah;
            }
        }
    }
    if (okL) lds[mis + t * 85 + 84] = fsig(Lv);
    __syncthreads();

    copy_phase_block(lds, dst, mis, W * 85);
}

__global__ __launch_bounds__(512, 8) void yolo_fused(
    const float* __restrict__ f13, const float* __restrict__ f26,
    float* __restrict__ out)
{
    __shared__ __align__(16) float lds[104 * 85 + 4];  // 35.4 KB -> 4 blk/CU
    // Bijective chunked XCD swizzle (NWG % 8 == 0): consecutive original
    // bids (adjacent tiles of one plane) -> same XCD, dispatch slots 8 apart.
    const int w   = blockIdx.x;
    const int bid = (w & 7) * (NWG / 8) + (w >> 3);
    if (bid < H26_BLOCKS) head26_body(f26, out, lds, bid);
    else                  head13_body(f13, out, lds, bid - H26_BLOCKS);
}

extern "C" void kernel_launch(void* const* d_in, const int* in_sizes, int n_in,
                              void* d_out, int out_size, void* d_ws, size_t ws_size,
                              hipStream_t stream) {
    const float* f13 = (const float*)d_in[0];
    const float* f26 = (const float*)d_in[1];
    float* out = (float*)d_out;
    yolo_fused<<<NWG, 512, 0, stream>>>(f13, f26, out);
}

// Round 15
// 69.773 us; speedup vs baseline: 1.2827x; 1.2819x over previous
//
#include <hip/hip_runtime.h>

// YOLO decode, fused: feat13 [256,255,13,13] + feat26 [256,255,26,26]
//   -> out [256, 2535, 85] fp32   (2535 = 3*169 + 3*676)
//
// R15 = R12 exactly (best: 69.8 us). R13/R14 falsified both system-scope
// streaming-store encodings (`sc0 sc1 nt`, `sc1 nt`): both cost ~28% on the
// write path with FETCH_SIZE unchanged -> no LLC allocation control exists
// for stores on this part; plain `nt` is optimal (R5 A/B).
//
// Roofline arithmetic: compulsory beyond-L2 traffic = input 220.6 MB +
// output 224 MB = 445 MB/replay (every byte crosses L2<->fabric once,
// whether reads hit L3 or HBM). 445 MB / 69.8 us = 6.37 TB/s = 101% of the
// 6.29 TB/s copy ceiling. Residual FETCH=108 MB matches LRU steady state
// for a 445 MB working set in 256 MB LLC.
//
// Structure (all A/B-proven):
//  - W=104 tiles, 512-thr blocks, 35.4 KB LDS (4 blk/CU, 32 waves).
//  - Full decode during staging; LDS holds FINAL values in output layout
//    (shifted by dst misalignment); store = pure ds_read_b128 ->
//    nontemporal global_store_dwordx4.
//  - head26 wave-autonomous (no block barrier; wave-local lgkmcnt fence).
//  - Bijective chunked XCD swizzle: same-plane tiles -> same XCD, dispatch
//    slots 8 apart (seam cache lines L2-hit; FETCH 140.8 -> 107.9 MB).

#define ROWS 2535
#define H26_BLOCKS (256 * 3 * 7)    // ceil(676/104) = 7 tiles (last W=52)
#define H13_BLOCKS (256 * 3 * 2)    // ceil(169/104) = 2 tiles (last W=65)
#define NWG (H26_BLOCKS + H13_BLOCKS)   // 6912, % 8 == 0

typedef float vf4 __attribute__((ext_vector_type(4)));

__device__ __forceinline__ float fsig(float v) {
    return __builtin_amdgcn_rcpf(1.0f + __expf(-v));
}

// ---- pure-copy store over [j_lo, j_hi) by one wave ----
__device__ __forceinline__ void copy_phase_wave(
    const float* __restrict__ lds, float* __restrict__ dst, int mis,
    int j_lo, int j_hi)
{
    const int lane = threadIdx.x & 63;
    const int kk  = (4 - ((mis + j_lo) & 3)) & 3;   // scalars to 16B boundary
    const int qlo = j_lo + kk;
    const int nq  = (j_hi - qlo) >> 2;

    if (lane < kk && j_lo + lane < j_hi)
        __builtin_nontemporal_store(lds[mis + j_lo + lane], dst + j_lo + lane);
    for (int q = lane; q < nq; q += 64) {
        int j0 = qlo + q * 4;
        const vf4 v = *(const vf4*)(lds + mis + j0);    // 16B-aligned b128
        __builtin_nontemporal_store(v, (vf4*)(dst + j0));
    }
    for (int j = qlo + nq * 4 + lane; j < j_hi; j += 64)
        __builtin_nontemporal_store(lds[mis + j], dst + j);
}

// ---- pure-copy store, block-wide (head13, after __syncthreads) ----
__device__ __forceinline__ void copy_phase_block(
    const float* __restrict__ lds, float* __restrict__ dst, int mis, int n)
{
    const int t  = threadIdx.x;
    const int kk = (4 - mis) & 3;
    const int nq = (n - kk) >> 2;
    if (t < kk)
        __builtin_nontemporal_store(lds[mis + t], dst + t);
    for (int q = t; q < nq; q += 512) {
        int j0 = q * 4 + kk;
        const vf4 v = *(const vf4*)(lds + mis + j0);
        __builtin_nontemporal_store(v, (vf4*)(dst + j0));
    }
    for (int j = kk + nq * 4 + t; j < n; j += 512)
        __builtin_nontemporal_store(lds[mis + j], dst + j);
}

__device__ __forceinline__ void head26_body(
    const float* __restrict__ f, float* __restrict__ out, float* __restrict__ lds,
    int bid)
{
    constexpr int GG = 676, TPP = 7;
    const int tile = bid % TPP;       // constexpr divisors -> magic mul
    const int ba   = bid / TPP;
    const int a    = ba % 3;
    const int b    = ba / 3;
    const int s0   = tile * 104;      // s0 % 26 == 0
    const int W    = (GG - s0 < 104) ? (GG - s0) : 104;   // 104 or 52
    const int C4   = W >> 2;          // 26 or 13 vf4-columns

    const float aw = (a == 0) ? 10.f : (a == 1) ? 23.f : 37.f;
    const float ah = (a == 0) ? 14.f : (a == 1) ? 27.f : 58.f;

    const float* __restrict__ src = f + (size_t)(b * 255 + a * 85) * GG + s0;
    float* __restrict__ dst = out + ((size_t)b * ROWS + 507 + (size_t)a * GG + s0) * 85;
    const int mis  = (int)(((size_t)dst >> 2) & 3);
    const int wave = threadIdx.x >> 6;
    const int lane = threadIdx.x & 63;

    // column split across 8 waves:
    //   C4=26: waves 0,1 -> 4 cols; waves 2..7 -> 3 cols
    //   C4=13: waves 0..4 -> 2 cols; waves 5..7 -> 1 col
    int lo, nw4;
    if (C4 == 26) { nw4 = (wave < 2) ? 4 : 3;
                    lo  = (wave < 2) ? wave * 4 : 8 + (wave - 2) * 3; }
    else          { nw4 = (wave < 5) ? 2 : 1;
                    lo  = (wave < 5) ? wave * 2 : 10 + (wave - 5); }
    const int nitems = 85 * nw4;      // <= 340 -> <= 6 rounds of 64 lanes

    // c-major item decomposition (wave-uniform divisor selection)
    #define DECOMP(i, c, w4r)                                   \
        do { if (nw4 == 4)      { c = (i) >> 2; w4r = (i) & 3; }\
             else if (nw4 == 3) { c = (i) / 3;  w4r = (i) - c * 3; }\
             else if (nw4 == 2) { c = (i) >> 1; w4r = (i) & 1; }\
             else               { c = (i);      w4r = 0; } } while (0)

    // ---- batched loads ----
    vf4 V[6];
    #pragma unroll
    for (int r = 0; r < 6; ++r) {
        int i = lane + r * 64;
        if (i < nitems) {
            int c, w4r; DECOMP(i, c, w4r);
            V[r] = *(const vf4*)(src + (size_t)c * GG + (lo + w4r) * 4);
        }
    }

    // ---- decode + LDS write (FINAL values; stride 85 = odd bank step) ----
    #pragma unroll
    for (int r = 0; r < 6; ++r) {
        int i = lane + r * 64;
        if (i < nitems) {
            int c, w4r; DECOMP(i, c, w4r);
            const int wb   = (lo + w4r) * 4;            // spatial w of V[r].x
            const int base = mis + wb * 85 + c;
            const vf4 v = V[r];
            if (c >= 4) {
                lds[base]       = fsig(v.x);
                lds[base + 85]  = fsig(v.y);
                lds[base + 170] = fsig(v.z);
                lds[base + 255] = fsig(v.w);
            } else if (c == 0) {
                #pragma unroll
                for (int e = 0; e < 4; ++e) {
                    int w = wb + e;
                    int k26 = w / 26;                   // const div, 0..3
                    int gx  = w - k26 * 26;
                    lds[base + e * 85] = (fsig(v[e]) + (float)gx) * 16.0f;
                }
            } else if (c == 1) {
                #pragma unroll
                for (int e = 0; e < 4; ++e) {
                    int w = wb + e;
                    int k26 = w / 26;
                    int gy  = tile * 4 + k26;           // s0/26 = tile*4
                    lds[base + e * 85] = (fsig(v[e]) + (float)gy) * 16.0f;
                }
            } else {
                #pragma unroll
                for (int e = 0; e < 4; ++e)
                    lds[base + e * 85] = __expf(v[e]) * ((c == 2) ? aw : ah);
            }
        }
    }
    #undef DECOMP

    // wave-local LDS fence (no block barrier)
    asm volatile("s_waitcnt lgkmcnt(0)" ::: "memory");
    __builtin_amdgcn_sched_barrier(0);

    copy_phase_wave(lds, dst, mis, lo * 340, (lo + nw4) * 340);
}

__device__ __forceinline__ void head13_body(
    const float* __restrict__ f, float* __restrict__ out, float* __restrict__ lds,
    int bid)
{
    constexpr int GG = 169, TPP = 2;
    const int tile = bid % TPP;
    const int ba   = bid / TPP;
    const int a    = ba % 3;
    const int b    = ba / 3;
    const int s0   = tile * 104;      // s0 % 13 == 0
    const int W    = (GG - s0 < 104) ? (GG - s0) : 104;   // 104, 65

    const float aw = (a == 0) ? 81.f : (a == 1) ? 135.f : 344.f;
    const float ah = (a == 0) ? 82.f : (a == 1) ? 169.f : 319.f;

    const float* __restrict__ src = f + (size_t)(b * 255 + a * 85) * GG;
    float* __restrict__ dst = out + ((size_t)b * ROWS + (size_t)a * GG + s0) * 85;
    const int mis = (int)(((size_t)dst >> 2) & 3);
    const int t = threadIdx.x;

    // ---- load phase: 42 pairs x 104 w-slots = 4368 items, 9 rounds ----
    float A[9], B[9], Lv;
    #pragma unroll
    for (int k = 0; k < 9; ++k) {
        int i = t + k * 512;
        int p = i / 104;              // const div
        int w = i - p * 104;
        if ((k < 8 || i < 4368) && (w < W)) {
            const float* s = src + (size_t)(2 * p) * GG + s0 + w;
            A[k] = s[0];
            B[k] = s[GG];
        }
    }
    const bool okL = t < W;                   // leftover channel c=84
    if (okL) Lv = src[(size_t)84 * GG + s0 + t];

    // ---- decode + write phase (FINAL values) ----
    #pragma unroll
    for (int k = 0; k < 9; ++k) {
        int i = t + k * 512;
        int p = i / 104;
        int w = i - p * 104;
        if ((k < 8 || i < 4368) && (w < W)) {
            int base = mis + w * 85 + 2 * p;
            if (p >= 2) {
                lds[base]     = fsig(A[k]);
                lds[base + 1] = fsig(B[k]);
            } else if (p == 0) {
                int t13 = w / 13;             // const div, 0..7
                int gx  = w - t13 * 13;
                int gy  = tile * 8 + t13;     // s0/13 = tile*8
                lds[base]     = (fsig(A[k]) + (float)gx) * 32.0f;
                lds[base + 1] = (fsig(B[k]) + (float)gy) * 32.0f;
            } else {
                lds[base]     = __expf(A[k]) * aw;
                lds[base + 1] = __expf(B[k]) * ah;
            }
        }
    }
    if (okL) lds[mis + t * 85 + 84] = fsig(Lv);
    __syncthreads();

    copy_phase_block(lds, dst, mis, W * 85);
}

__global__ __launch_bounds__(512, 8) void yolo_fused(
    const float* __restrict__ f13, const float* __restrict__ f26,
    float* __restrict__ out)
{
    __shared__ __align__(16) float lds[104 * 85 + 4];  // 35.4 KB -> 4 blk/CU
    // Bijective chunked XCD swizzle (NWG % 8 == 0): consecutive original
    // bids (adjacent tiles of one plane) -> same XCD, dispatch slots 8 apart.
    const int w   = blockIdx.x;
    const int bid = (w & 7) * (NWG / 8) + (w >> 3);
    if (bid < H26_BLOCKS) head26_body(f26, out, lds, bid);
    else                  head13_body(f13, out, lds, bid - H26_BLOCKS);
}

extern "C" void kernel_launch(void* const* d_in, const int* in_sizes, int n_in,
                              void* d_out, int out_size, void* d_ws, size_t ws_size,
                              hipStream_t stream) {
    const float* f13 = (const float*)d_in[0];
    const float* f26 = (const float*)d_in[1];
    float* out = (float*)d_out;
    yolo_fused<<<NWG, 512, 0, stream>>>(f13, f26, out);
}